// Round 3
// baseline (325.108 us; speedup 1.0000x reference)
//
#include <hip/hip_runtime.h>
#include <math.h>

#define BATCH 32
#define N 160
#define CH 3
#define LDIM 128
#define OUT 150          // N - 11 + 1
#define P 38             // (160-12)/4 + 1

#define SSIM_TILES 19
#define SSIM_BLOCKS (SSIM_TILES*CH*BATCH)      // 1824
#define STFT_PRG 19                            // 2 pr per block, 19*2 = 38 exactly
#define STFT_BLOCKS (STFT_PRG*CH*BATCH)        // 1824
#define TOTAL_PARTIALS (SSIM_BLOCKS + STFT_BLOCKS) // 3648

// e^{-i*2pi*k/12} tables (compile-time folded in fully unrolled loops)
__device__ constexpr float TWC[12] = { 1.f, 0.86602540f, 0.5f, 0.f, -0.5f, -0.86602540f,
                                      -1.f,-0.86602540f,-0.5f, 0.f,  0.5f,  0.86602540f};
__device__ constexpr float TWS[12] = { 0.f,-0.5f,-0.86602540f,-1.f,-0.86602540f,-0.5f,
                                       0.f, 0.5f, 0.86602540f, 1.f, 0.86602540f, 0.5f};

// normalized gaussian(11, sigma=1.5), precomputed at double precision
__device__ constexpr float GW[11] = {0.00102838f, 0.00759876f, 0.03600076f, 0.10936070f,
                                     0.21300554f, 0.26601172f, 0.21300554f, 0.10936070f,
                                     0.03600076f, 0.00759876f, 0.00102838f};

template<int NWAVES>
__device__ __forceinline__ float block_sum(float v) {
    #pragma unroll
    for (int o = 32; o > 0; o >>= 1) v += __shfl_down(v, o, 64);
    __shared__ float sm[NWAVES];
    int w = threadIdx.x >> 6;
    if ((threadIdx.x & 63) == 0) sm[w] = v;
    __syncthreads();
    if (threadIdx.x == 0) {
        v = sm[0];
        #pragma unroll
        for (int i = 1; i < NWAVES; ++i) v += sm[i];
    }
    return v;
}

// ---------------- SSIM ----------------
// block = (tile of 8 output rows, c, b), 320 threads. Separable gaussian:
// phase1 stage 18 rows; phase2 vertical 11-tap (float4-wide) -> 5 planes;
// phase3 horizontal 11-tap from a 16-float register window + SSIM formula.
__global__ __launch_bounds__(320, 4) void ssim_kernel(const float* __restrict__ xin,
                                                      const float* __restrict__ xout,
                                                      float* __restrict__ partial) {
    __shared__ __align__(16) float sx[18 * 160];
    __shared__ __align__(16) float sy[18 * 160];
    __shared__ __align__(16) float V[5][8 * 160 + 16];   // pad 16 for window over-read

    const int tile = blockIdx.x, c = blockIdx.y, b = blockIdx.z;
    const int tid = threadIdx.x;
    const int r0 = tile * 8;

    // phase 1: stage rows r0..r0+17 (zero-fill past image bottom)
    {
        int col = tid % 160;
        int rb  = tid / 160;          // 0 or 1
        #pragma unroll
        for (int k = 0; k < 9; ++k) {
            int r = rb + 2 * k;       // 0..17
            int row = r0 + r;
            float vx = 0.f, vy = 0.f;
            if (row < N) {
                size_t off = (((size_t)b * N + row) * N + col) * CH + c;
                vx = xin[off]; vy = xout[off];
            }
            sx[r * 160 + col] = vx;
            sy[r * 160 + col] = vy;
        }
    }
    __syncthreads();

    // phase 2: vertical 11-tap, one thread = (orow, 4 cols). 8*40 = 320 tasks.
    {
        int orow = tid / 40;
        int cbase = (tid % 40) * 4;
        float ax[4] = {0,0,0,0}, ay[4] = {0,0,0,0};
        float axx[4] = {0,0,0,0}, ayy[4] = {0,0,0,0}, axy[4] = {0,0,0,0};
        #pragma unroll
        for (int k = 0; k < 11; ++k) {
            float4 qx = *(const float4*)&sx[(orow + k) * 160 + cbase];
            float4 qy = *(const float4*)&sy[(orow + k) * 160 + cbase];
            float w = GW[k];
            float xs[4] = {qx.x, qx.y, qx.z, qx.w};
            float ys[4] = {qy.x, qy.y, qy.z, qy.w};
            #pragma unroll
            for (int o = 0; o < 4; ++o) {
                ax[o]  += w * xs[o];          ay[o]  += w * ys[o];
                axx[o] += w * (xs[o]*xs[o]);  ayy[o] += w * (ys[o]*ys[o]);
                axy[o] += w * (xs[o]*ys[o]);
            }
        }
        int base = orow * 160 + cbase;
        *(float4*)&V[0][base] = make_float4(ax[0],  ax[1],  ax[2],  ax[3]);
        *(float4*)&V[1][base] = make_float4(ay[0],  ay[1],  ay[2],  ay[3]);
        *(float4*)&V[2][base] = make_float4(axx[0], axx[1], axx[2], axx[3]);
        *(float4*)&V[3][base] = make_float4(ayy[0], ayy[1], ayy[2], ayy[3]);
        *(float4*)&V[4][base] = make_float4(axy[0], axy[1], axy[2], axy[3]);
    }
    __syncthreads();

    // phase 3: horizontal 11-tap + SSIM. tasks = 8 rows * 38 col-groups = 304.
    float acc = 0.f;
    if (tid < 304) {
        int orow = tid / 38;
        int oc = (tid % 38) * 4;
        float st[5][4];               // mx,my,sxx,syy,sxy per output
        #pragma unroll
        for (int p = 0; p < 5; ++p) {
            float vals[16];
            #pragma unroll
            for (int q = 0; q < 4; ++q) {
                float4 t4 = *(const float4*)&V[p][orow * 160 + oc + 4 * q];
                vals[4*q+0] = t4.x; vals[4*q+1] = t4.y; vals[4*q+2] = t4.z; vals[4*q+3] = t4.w;
            }
            #pragma unroll
            for (int o = 0; o < 4; ++o) {
                float s = 0.f;
                #pragma unroll
                for (int k = 0; k < 11; ++k) s += GW[k] * vals[o + k];
                st[p][o] = s;
            }
        }
        const float c1 = 1e-4f, c2 = 9e-4f;
        #pragma unroll
        for (int o = 0; o < 4; ++o) {
            if (r0 + orow < OUT && oc + o < OUT) {
                float mx = st[0][o], my = st[1][o];
                float vx = st[2][o] - mx * mx;
                float vy = st[3][o] - my * my;
                float cv = st[4][o] - mx * my;
                float lum = (2.f * mx * my + c1) / (mx * mx + my * my + c1);
                float cs  = (2.f * cv + c2) / (vx + vy + c2);
                acc += lum * cs;
            }
        }
    }
    acc *= 1.f / (32.f * 150.f * 150.f * 3.f);
    float s = block_sum<5>(acc);
    if (tid == 0) partial[blockIdx.x + SSIM_TILES * (blockIdx.y + CH * blockIdx.z)] = s;
}

// ---------------- STFT ----------------
// block = (prg, c, b), 384 threads; prg covers pr = {2*prg, 2*prg+1} -> rows
// r0=8*prg .. r0+15. Phase A: row DFT per (img, r, pc) direct from global
// (row redundancy 2x instead of 3x). Phase B: column DFT per (g, pc, u) over
// all 5 v with contiguous float4 RD loads + LDS twiddle table (no recurrence).
__global__ __launch_bounds__(384, 4) void stft_kernel(const float* __restrict__ xin,
                                                      const float* __restrict__ xout,
                                                      float* __restrict__ partial) {
    __shared__ __align__(16) float RD[16 * 38 * 20]; // [r][pc][vv*4 + img*2 + {re,im}]
    __shared__ float TWT[5][12][2];                  // [u-1][i][{cos,-sin}]

    const int prg = blockIdx.x, c = blockIdx.y, b = blockIdx.z;
    const int tid = threadIdx.x;
    const int row0 = prg * 8;

    // fill twiddle table: theta = 2*pi*u*i/12
    if (tid < 60) {
        int uu = tid / 12, i = tid % 12;
        float sn, cs;
        sincosf((float)((uu + 1) * i) * 0.5235987755982988f, &sn, &cs);
        TWT[uu][i][0] = cs; TWT[uu][i][1] = -sn;
    }

    // phase A: 2*16*38 = 1216 row-DFT tasks
    for (int t = tid; t < 1216; t += 384) {
        int pc = t % 38;
        int rem = t / 38;           // 0..31
        int r = rem & 15;
        int img = rem >> 4;
        const float* src = img ? xout : xin;
        const float* p = src + (((size_t)b * N + row0 + r) * N + pc * 4) * CH + c;
        float x[12];
        #pragma unroll
        for (int j = 0; j < 12; ++j) x[j] = p[j * 3];
        float rre[5] = {0,0,0,0,0}, rim[5] = {0,0,0,0,0};
        #pragma unroll
        for (int j = 0; j < 12; ++j) {
            #pragma unroll
            for (int vv = 0; vv < 5; ++vv) {
                int k = ((vv + 1) * j) % 12;   // compile-time
                rre[vv] += x[j] * TWC[k];
                rim[vv] += x[j] * TWS[k];
            }
        }
        float* w = &RD[(r * 38 + pc) * 20 + img * 2];
        #pragma unroll
        for (int vv = 0; vv < 5; ++vv) {
            w[vv * 4 + 0] = rre[vv];
            w[vv * 4 + 1] = rim[vv];
        }
    }
    __syncthreads();

    // phase B: 2*38*5 = 380 column-DFT tasks (each covers all 5 v)
    float acc = 0.f;
    if (tid < 380) {
        int t = tid;
        int uu = t % 5;             // u-1
        int rem = t / 5;
        int pc = rem % 38;
        int g = rem / 38;           // local pr
        float FinR[5] = {0,0,0,0,0}, FinI[5] = {0,0,0,0,0};
        float FoutR[5] = {0,0,0,0,0}, FoutI[5] = {0,0,0,0,0};
        #pragma unroll
        for (int i = 0; i < 12; ++i) {
            float cu = TWT[uu][i][0], su = TWT[uu][i][1];
            const float4* q4 = (const float4*)&RD[((4 * g + i) * 38 + pc) * 20];
            #pragma unroll
            for (int vv = 0; vv < 5; ++vv) {
                float4 q = q4[vv];
                FinR[vv]  += cu * q.x - su * q.y;
                FinI[vv]  += cu * q.y + su * q.x;
                FoutR[vv] += cu * q.z - su * q.w;
                FoutI[vv] += cu * q.w + su * q.z;
            }
        }
        #pragma unroll
        for (int vv = 0; vv < 5; ++vv) {
            float aI = atan2f(FinI[vv],  FinR[vv]  + 1e-8f);
            float aO = atan2f(FoutI[vv], FoutR[vv] + 1e-8f);
            float mI = sqrtf(FinR[vv] * FinR[vv] + FinI[vv] * FinI[vv]);
            float mO = sqrtf(FoutR[vv] * FoutR[vv] + FoutI[vv] * FoutI[vv]);
            float ff = (float)((uu + 1) * (vv + 1)) * 0.04f;
            acc += ff * (fabsf(aO - aI) + fabsf(mO - mI));
        }
    }
    acc *= 1e-4f / 32.f;
    float s = block_sum<6>(acc);
    if (tid == 0)
        partial[SSIM_BLOCKS + blockIdx.x + STFT_PRG * (blockIdx.y + CH * blockIdx.z)] = s;
}

// ---------------- final reduce (+ KLD inline) ----------------
__global__ __launch_bounds__(256) void final_kernel(const float* __restrict__ mean,
                                                    const float* __restrict__ logvar,
                                                    const float* __restrict__ partial,
                                                    float* __restrict__ out) {
    float a = 0.f;
    for (int i = threadIdx.x; i < BATCH * LDIM; i += 256) {
        float m = mean[i], lv = logvar[i];
        a += -0.5f * (1.f + lv - expf(lv) - m * m) * (1.f / 32.f);
    }
    for (int i = threadIdx.x; i < TOTAL_PARTIALS; i += 256) a += partial[i];
    float s = block_sum<4>(a);
    if (threadIdx.x == 0) out[0] = s;
}

extern "C" void kernel_launch(void* const* d_in, const int* in_sizes, int n_in,
                              void* d_out, int out_size, void* d_ws, size_t ws_size,
                              hipStream_t stream) {
    const float* mean   = (const float*)d_in[0];
    const float* logvar = (const float*)d_in[1];
    const float* xin    = (const float*)d_in[2];
    const float* xout   = (const float*)d_in[3];
    float* out = (float*)d_out;
    float* partial = (float*)d_ws;

    ssim_kernel<<<dim3(SSIM_TILES, CH, BATCH), 320, 0, stream>>>(xin, xout, partial);
    stft_kernel<<<dim3(STFT_PRG, CH, BATCH), 384, 0, stream>>>(xin, xout, partial);
    final_kernel<<<1, 256, 0, stream>>>(mean, logvar, partial, out);
}

// Round 4
// 229.108 us; speedup vs baseline: 1.4190x; 1.4190x over previous
//
#include <hip/hip_runtime.h>
#include <math.h>

#define BATCH 32
#define N 160
#define CH 3
#define LDIM 128
#define OUT 150          // N - 11 + 1
#define P 38             // (160-12)/4 + 1

#define SSIM_TILES 19
#define SSIM_BLOCKS (SSIM_TILES*CH*BATCH)      // 1824
#define STFT_PRG 19                            // 2 pr per block
#define STFT_BLOCKS (STFT_PRG*CH*BATCH)        // 1824
#define TOTAL_PARTIALS (SSIM_BLOCKS + STFT_BLOCKS) // 3648

#define RSTRIDE 164                            // padded LDS row stride (floats)

// e^{-i*2pi*k/12} (compile-time folded where loops unroll)
__device__ constexpr float TWC[12] = { 1.f, 0.86602540f, 0.5f, 0.f, -0.5f, -0.86602540f,
                                      -1.f,-0.86602540f,-0.5f, 0.f,  0.5f,  0.86602540f};
__device__ constexpr float TWS[12] = { 0.f,-0.5f,-0.86602540f,-1.f,-0.86602540f,-0.5f,
                                       0.f, 0.5f, 0.86602540f, 1.f, 0.86602540f, 0.5f};

// normalized gaussian(11, sigma=1.5)
__device__ constexpr float GW[11] = {0.00102838f, 0.00759876f, 0.03600076f, 0.10936070f,
                                     0.21300554f, 0.26601172f, 0.21300554f, 0.10936070f,
                                     0.03600076f, 0.00759876f, 0.00102838f};

template<int NWAVES>
__device__ __forceinline__ float block_sum(float v) {
    #pragma unroll
    for (int o = 32; o > 0; o >>= 1) v += __shfl_down(v, o, 64);
    __shared__ float sm[NWAVES];
    int w = threadIdx.x >> 6;
    if ((threadIdx.x & 63) == 0) sm[w] = v;
    __syncthreads();
    if (threadIdx.x == 0) {
        v = sm[0];
        #pragma unroll
        for (int i = 1; i < NWAVES; ++i) v += sm[i];
    }
    return v;
}

// ---------------- SSIM ----------------
// block = (tile of 8 output rows, c, b), 320 threads, NO min-wave cap.
__global__ __launch_bounds__(320) void ssim_kernel(const float* __restrict__ xin,
                                                   const float* __restrict__ xout,
                                                   float* __restrict__ partial) {
    __shared__ __align__(16) float sx[18 * 160];
    __shared__ __align__(16) float sy[18 * 160];
    __shared__ __align__(16) float V[5][8 * 160 + 16];   // pad for window over-read

    const int tile = blockIdx.x, c = blockIdx.y, b = blockIdx.z;
    const int tid = threadIdx.x;
    const int r0 = tile * 8;

    // phase 1: 320 threads = 160 cols x 2 images; 18 rows each (zero-fill past bottom)
    {
        int col = tid % 160;
        int img = tid / 160;
        const float* src = img ? xout : xin;
        float* dst = img ? sy : sx;
        #pragma unroll
        for (int r = 0; r < 18; ++r) {
            int row = r0 + r;
            float v = 0.f;
            if (row < N) v = src[(((size_t)b * N + row) * N + col) * CH + c];
            dst[r * 160 + col] = v;
        }
    }
    __syncthreads();

    // phase 2: vertical 11-tap, thread = (orow, 4 cols): 8*40 = 320 tasks exactly
    {
        int orow = tid / 40;
        int cbase = (tid % 40) * 4;
        float ax[4] = {0,0,0,0}, ay[4] = {0,0,0,0};
        float axx[4] = {0,0,0,0}, ayy[4] = {0,0,0,0}, axy[4] = {0,0,0,0};
        #pragma unroll
        for (int k = 0; k < 11; ++k) {
            float4 qx = *(const float4*)&sx[(orow + k) * 160 + cbase];
            float4 qy = *(const float4*)&sy[(orow + k) * 160 + cbase];
            float w = GW[k];
            float xs[4] = {qx.x, qx.y, qx.z, qx.w};
            float ys[4] = {qy.x, qy.y, qy.z, qy.w};
            #pragma unroll
            for (int o = 0; o < 4; ++o) {
                ax[o]  += w * xs[o];          ay[o]  += w * ys[o];
                axx[o] += w * (xs[o]*xs[o]);  ayy[o] += w * (ys[o]*ys[o]);
                axy[o] += w * (xs[o]*ys[o]);
            }
        }
        int base = orow * 160 + cbase;
        *(float4*)&V[0][base] = make_float4(ax[0],  ax[1],  ax[2],  ax[3]);
        *(float4*)&V[1][base] = make_float4(ay[0],  ay[1],  ay[2],  ay[3]);
        *(float4*)&V[2][base] = make_float4(axx[0], axx[1], axx[2], axx[3]);
        *(float4*)&V[3][base] = make_float4(ayy[0], ayy[1], ayy[2], ayy[3]);
        *(float4*)&V[4][base] = make_float4(axy[0], axy[1], axy[2], axy[3]);
    }
    __syncthreads();

    // phase 3: horizontal 11-tap + SSIM. 8 rows * 38 col-quads = 304 tasks.
    float acc = 0.f;
    if (tid < 304) {
        int orow = tid / 38;
        int oc = (tid % 38) * 4;
        float st[5][4];
        #pragma unroll
        for (int p = 0; p < 5; ++p) {
            float vals[16];
            #pragma unroll
            for (int q = 0; q < 4; ++q) {
                float4 t4 = *(const float4*)&V[p][orow * 160 + oc + 4 * q];
                vals[4*q+0] = t4.x; vals[4*q+1] = t4.y; vals[4*q+2] = t4.z; vals[4*q+3] = t4.w;
            }
            #pragma unroll
            for (int o = 0; o < 4; ++o) {
                float s = 0.f;
                #pragma unroll
                for (int k = 0; k < 11; ++k) s += GW[k] * vals[o + k];
                st[p][o] = s;
            }
        }
        const float c1 = 1e-4f, c2 = 9e-4f;
        #pragma unroll
        for (int o = 0; o < 4; ++o) {
            if (r0 + orow < OUT && oc + o < OUT) {
                float mx = st[0][o], my = st[1][o];
                float vx = st[2][o] - mx * mx;
                float vy = st[3][o] - my * my;
                float cv = st[4][o] - mx * my;
                float lum = (2.f * mx * my + c1) / (mx * mx + my * my + c1);
                float cs  = (2.f * cv + c2) / (vx + vy + c2);
                acc += lum * cs;
            }
        }
    }
    acc *= 1.f / (32.f * 150.f * 150.f * 3.f);
    float s = block_sum<5>(acc);
    if (tid == 0) partial[blockIdx.x + SSIM_TILES * (blockIdx.y + CH * blockIdx.z)] = s;
}

// ---------------- STFT ----------------
// block = (prg, c, b), 384 threads; covers pr = {2*prg, 2*prg+1} -> rows
// row0 = 8*prg .. row0+15. Images processed sequentially so a single 16-row
// LDS staging buffer is reused (keeps total LDS under 64 KB).
// Phase A: stage rows coalesced; row DFT per (r, pc) -> RD[r][pc][vv][img].
// Phase B: column DFT per (g, pc, u) over all 5 v with float4 RD loads +
// LDS twiddle table.
__global__ __launch_bounds__(384) void stft_kernel(const float* __restrict__ xin,
                                                   const float* __restrict__ xout,
                                                   float* __restrict__ partial) {
    __shared__ __align__(16) float rows[16 * RSTRIDE];   // 10496 B
    __shared__ __align__(16) float RD[16 * 38 * 20];     // 48640 B
    __shared__ float TWT[5][12][2];                      // 480 B

    const int prg = blockIdx.x, c = blockIdx.y, b = blockIdx.z;
    const int tid = threadIdx.x;
    const int row0 = prg * 8;

    // twiddle table: e^{-i*2pi*u*i/12}, u = uu+1
    if (tid < 60) {
        int uu = tid / 12, i = tid % 12;
        float sn, cs;
        sincosf((float)((uu + 1) * i) * 0.5235987755982988f, &sn, &cs);
        TWT[uu][i][0] = cs; TWT[uu][i][1] = -sn;
    }

    for (int img = 0; img < 2; ++img) {
        const float* src = img ? xout : xin;
        // stage: 16 rows x 160 cols, coalesced over col
        for (int t = tid; t < 16 * 160; t += 384) {
            int r = t / 160, col = t % 160;
            rows[r * RSTRIDE + col] = src[(((size_t)b * N + row0 + r) * N + col) * CH + c];
        }
        __syncthreads();
        // row DFT: 16*38 = 608 tasks, r fastest
        for (int t = tid; t < 608; t += 384) {
            int r = t & 15, pc = t >> 4;
            const float4* rp = (const float4*)&rows[r * RSTRIDE + pc * 4];
            float4 q0 = rp[0], q1 = rp[1], q2 = rp[2];
            float x[12] = {q0.x,q0.y,q0.z,q0.w, q1.x,q1.y,q1.z,q1.w, q2.x,q2.y,q2.z,q2.w};
            float rre[5] = {0,0,0,0,0}, rim[5] = {0,0,0,0,0};
            #pragma unroll
            for (int j = 0; j < 12; ++j) {
                #pragma unroll
                for (int vv = 0; vv < 5; ++vv) {
                    int k = ((vv + 1) * j) % 12;   // compile-time
                    rre[vv] += x[j] * TWC[k];
                    rim[vv] += x[j] * TWS[k];
                }
            }
            float* w = &RD[(r * 38 + pc) * 20 + img * 2];
            #pragma unroll
            for (int vv = 0; vv < 5; ++vv) {
                w[vv * 4 + 0] = rre[vv];
                w[vv * 4 + 1] = rim[vv];
            }
        }
        __syncthreads();
    }

    // phase B: 2*38*5 = 380 tasks = (g, pc, uu), each covers all 5 v
    float acc = 0.f;
    if (tid < 380) {
        int uu = tid % 5;
        int rem = tid / 5;
        int pc = rem % 38;
        int g  = rem / 38;               // local pr; rows used: 4g .. 4g+11
        float FinR[5] = {0,0,0,0,0}, FinI[5] = {0,0,0,0,0};
        float FoutR[5] = {0,0,0,0,0}, FoutI[5] = {0,0,0,0,0};
        #pragma unroll
        for (int i = 0; i < 12; ++i) {
            float cu = TWT[uu][i][0], su = TWT[uu][i][1];
            const float4* q4 = (const float4*)&RD[((4 * g + i) * 38 + pc) * 20];
            #pragma unroll
            for (int vv = 0; vv < 5; ++vv) {
                float4 q = q4[vv];
                FinR[vv]  += cu * q.x - su * q.y;
                FinI[vv]  += cu * q.y + su * q.x;
                FoutR[vv] += cu * q.z - su * q.w;
                FoutI[vv] += cu * q.w + su * q.z;
            }
        }
        #pragma unroll
        for (int vv = 0; vv < 5; ++vv) {
            float aI = atan2f(FinI[vv],  FinR[vv]  + 1e-8f);
            float aO = atan2f(FoutI[vv], FoutR[vv] + 1e-8f);
            float mI = sqrtf(FinR[vv] * FinR[vv] + FinI[vv] * FinI[vv]);
            float mO = sqrtf(FoutR[vv] * FoutR[vv] + FoutI[vv] * FoutI[vv]);
            float ff = (float)((uu + 1) * (vv + 1)) * 0.04f;
            acc += ff * (fabsf(aO - aI) + fabsf(mO - mI));
        }
    }
    acc *= 1e-4f / 32.f;
    float s = block_sum<6>(acc);
    if (tid == 0)
        partial[SSIM_BLOCKS + blockIdx.x + STFT_PRG * (blockIdx.y + CH * blockIdx.z)] = s;
}

// ---------------- final reduce (+ KLD inline) ----------------
__global__ __launch_bounds__(256) void final_kernel(const float* __restrict__ mean,
                                                    const float* __restrict__ logvar,
                                                    const float* __restrict__ partial,
                                                    float* __restrict__ out) {
    float a = 0.f;
    for (int i = threadIdx.x; i < BATCH * LDIM; i += 256) {
        float m = mean[i], lv = logvar[i];
        a += -0.5f * (1.f + lv - expf(lv) - m * m) * (1.f / 32.f);
    }
    for (int i = threadIdx.x; i < TOTAL_PARTIALS; i += 256) a += partial[i];
    float s = block_sum<4>(a);
    if (threadIdx.x == 0) out[0] = s;
}

extern "C" void kernel_launch(void* const* d_in, const int* in_sizes, int n_in,
                              void* d_out, int out_size, void* d_ws, size_t ws_size,
                              hipStream_t stream) {
    const float* mean   = (const float*)d_in[0];
    const float* logvar = (const float*)d_in[1];
    const float* xin    = (const float*)d_in[2];
    const float* xout   = (const float*)d_in[3];
    float* out = (float*)d_out;
    float* partial = (float*)d_ws;

    ssim_kernel<<<dim3(SSIM_TILES, CH, BATCH), 320, 0, stream>>>(xin, xout, partial);
    stft_kernel<<<dim3(STFT_PRG, CH, BATCH), 384, 0, stream>>>(xin, xout, partial);
    final_kernel<<<1, 256, 0, stream>>>(mean, logvar, partial, out);
}